// Round 5
// baseline (191.487 us; speedup 1.0000x reference)
//
#include <hip/hip_runtime.h>
#include <math.h>

// Problem constants (B,S,D,P,C,V) = (64,128,2048,118,2,512)
#define NB 64
#define NS 128
#define ND 2048
#define NP 118
#define NC 2
#define NV 512

// Block partitioning
constexpr int RECON_BLOCKS = 512;   // persistent streaming, 4 waves/block
constexpr int KLD_BLOCKS   = 128;   // persistent streaming
constexpr int PTS_BLOCKS   = 512;   // one-shot, 16 rows (944 vec4) per block
constexpr int BEST_BLOCKS  = 16;    // one-shot
constexpr int TOTAL_BLOCKS = RECON_BLOCKS + KLD_BLOCKS + PTS_BLOCKS + BEST_BLOCKS; // 1168

constexpr int RECON_WAVES = RECON_BLOCKS * 4;     // 2048
constexpr int RECON_UNITS = (NB*NS*ND/4) / 256;   // 16384 units of 256 vec4 -> 8/wave
constexpr int KLD_WAVES   = KLD_BLOCKS * 4;       // 512
constexpr int KLD_UNITS   = (NB*NS*NV/4) / 256;   // 4096 -> 8/wave

// unit u of recon: zs vec4 range [u*256, u*256+256); row = u>>1, b = u>>8,
// rzs base vec4 = (b<<16) + (m<<9) + ((u&1)<<8)

#define RISSUE(Z, R, uu, mm) do {                                          \
    const float4* zp_ = z4 + (((size_t)(uu)) << 8) + lane;                 \
    Z[0] = zp_[0]; Z[1] = zp_[64]; Z[2] = zp_[128]; Z[3] = zp_[192];       \
    const float4* rp_ = r4 + (size_t)((((uu) >> 8) << 16) + ((mm) << 9)    \
                                      + (((uu) & 1) << 8)) + lane;         \
    R[0] = rp_[0]; R[1] = rp_[64]; R[2] = rp_[128]; R[3] = rp_[192];       \
  } while (0)

#define RCONS(Z, R, sacc) do {                                             \
    _Pragma("unroll")                                                      \
    for (int j_ = 0; j_ < 4; ++j_) {                                       \
        float dx = R[j_].x - Z[j_].x, dy = R[j_].y - Z[j_].y;              \
        float dz = R[j_].z - Z[j_].z, dw = R[j_].w - Z[j_].w;              \
        sacc += dx*dx + dy*dy + dz*dz + dw*dw;                             \
    }                                                                      \
  } while (0)

#define QISSUE(Q, uu) do {                                                 \
    const float4* qp_ = q4 + (((size_t)(uu)) << 8) + lane;                 \
    Q[0] = qp_[0]; Q[1] = qp_[64]; Q[2] = qp_[128]; Q[3] = qp_[192];       \
  } while (0)

#define QCONS(Q, sacc) do {                                                \
    _Pragma("unroll")                                                      \
    for (int j_ = 0; j_ < 4; ++j_) {                                       \
        sacc += Q[j_].x * (__logf(Q[j_].x + 1e-20f) - log_g)               \
              + Q[j_].y * (__logf(Q[j_].y + 1e-20f) - log_g)               \
              + Q[j_].z * (__logf(Q[j_].z + 1e-20f) - log_g)               \
              + Q[j_].w * (__logf(Q[j_].w + 1e-20f) - log_g);              \
    }                                                                      \
  } while (0)

__global__ __launch_bounds__(256) void cq_main(
    const float* __restrict__ zs, const float* __restrict__ rzs,
    const float* __restrict__ pts, const float* __restrict__ pts_gt,
    const float* __restrict__ qy,
    const float* __restrict__ best, const float* __restrict__ best_gt,
    const int* __restrict__ mapping, const int* __restrict__ vd,
    float* __restrict__ partials)
{
    const float w_recon = 1.0f / 16777216.0f;          // GAMMA / (B*S*D)
    const float w_kld   = 0.1f / 8192.0f;              // BETA / (B*S)
    const float w_disk  = 1.0f / 1933312.0f;           // 1 / (B*S*P*C)
    const float w_land  = 10.0f / 65536.0f;            // ALPHA / (B*S*4*C)
    const float w_best  = 1.0f / 15104.0f;             // 1 / (B*P*C)
    const float w_bland = 10.0f / 512.0f;              // ALPHA / (B*4*C)

    const int t    = threadIdx.x;
    const int blk  = blockIdx.x;
    const int lane = t & 63;
    float acc = 0.0f;

    __shared__ int mrow[16];   // pts region only

    if (blk < RECON_BLOCKS) {
        // ---- recon: persistent wave streams 8 units of 256 vec4, A/B pipelined
        const int gw = (blk << 2) + (t >> 6);          // 0..2047
        const float4* z4 = (const float4*)zs;
        const float4* r4 = (const float4*)rzs;
        float4 zA[4], rA[4], zB[4], rB[4];
        float s = 0.0f;

        int u = gw;
        int mA = mapping[u >> 1];
        RISSUE(zA, rA, u, mA);                         // prologue: A(u0)
        int mn = mapping[(u + RECON_WAVES) >> 1];      // m for u1
        #pragma unroll 1
        for (int i = 0; i < 3; ++i) {
            const int ub = u + RECON_WAVES;
            RISSUE(zB, rB, ub, mn);                    // issue B(u_{2i+1})
            const int mn2 = mapping[(ub + RECON_WAVES) >> 1];
            RCONS(zA, rA, s);                          // consume A(u_{2i})
            const int ua = ub + RECON_WAVES;
            RISSUE(zA, rA, ua, mn2);                   // issue A(u_{2i+2})
            mn = mapping[(ua + RECON_WAVES) >> 1];
            RCONS(zB, rB, s);                          // consume B(u_{2i+1})
            u = ua;
        }
        {   // tail: u = u0+6W; issue B(u0+7W), consume A, consume B
            const int ub = u + RECON_WAVES;
            RISSUE(zB, rB, ub, mn);
            RCONS(zA, rA, s);
            RCONS(zB, rB, s);
        }
        acc = w_recon * s;
    } else if (blk < RECON_BLOCKS + KLD_BLOCKS) {
        // ---- kld: persistent wave streams 8 units of 256 vec4, A/B pipelined
        const int gw = ((blk - RECON_BLOCKS) << 2) + (t >> 6);   // 0..511
        const float log_g = -__logf((float)vd[0]);               // log(1/V)
        const float4* q4 = (const float4*)qy;
        float4 qA[4], qB[4];
        float s = 0.0f;

        int u = gw;
        QISSUE(qA, u);
        #pragma unroll 1
        for (int i = 0; i < 3; ++i) {
            const int ub = u + KLD_WAVES;
            QISSUE(qB, ub);
            QCONS(qA, s);
            const int ua = ub + KLD_WAVES;
            QISSUE(qA, ua);
            QCONS(qB, s);
            u = ua;
        }
        {
            const int ub = u + KLD_WAVES;
            QISSUE(qB, ub);
            QCONS(qA, s);
            QCONS(qB, s);
        }
        acc = w_kld * s;
    } else if (blk < RECON_BLOCKS + KLD_BLOCKS + PTS_BLOCKS) {
        // ---- pts: disk + ALPHA*landmark over gathered rows; 16 rows per block
        const int rb = blk - (RECON_BLOCKS + KLD_BLOCKS);
        if (t < 16) mrow[t] = mapping[(rb << 4) + t];
        __syncthreads();
        const int bs_base = rb << 4;
        float4 x[4], g[4];
        int pbase[4];
        #pragma unroll
        for (int j = 0; j < 4; ++j) {
            const int w = t + j * 256;
            const unsigned rl = (unsigned)w / 59u;     // row_local
            const int qo = w - (int)rl * 59;
            const bool valid = (w < 944);
            const int rl_c = valid ? (int)rl : 0;
            const int bs = bs_base + rl_c;
            const int b  = bs >> 7;
            const int m  = mrow[rl_c];
            const size_t xi = (size_t)((b << 7) + m) * 236 + (qo << 2);
            const size_t gi = (size_t)(rb * 944 + w) << 2;
            pbase[j] = valid ? (qo << 1) : -100;
            x[j] = valid ? *(const float4*)(pts    + xi) : make_float4(0,0,0,0);
            g[j] = valid ? *(const float4*)(pts_gt + gi) : make_float4(0,0,0,0);
        }
        #pragma unroll
        for (int j = 0; j < 4; ++j) {
            const float* xp = (const float*)&x[j];
            const float* gp = (const float*)&g[j];
            #pragma unroll
            for (int jj = 0; jj < 4; ++jj) {
                const int p = pbase[j] + (jj >> 1);
                const bool marked = (p == 0) | (p == 29) | (p == 88) | (p == 117);
                const float wgt = w_disk + (marked ? w_land : 0.0f);
                const float d = xp[jj] - gp[jj];
                acc += wgt * d * d;
            }
        }
    } else {
        // ---- best: full mse + ALPHA*landmark, 236 vec4 per block
        const int db = blk - (RECON_BLOCKS + KLD_BLOCKS + PTS_BLOCKS);
        if (t < 236) {
            const int l = db * 236 + t;                // global vec4 index
            const unsigned bq = (unsigned)l / 59u;
            const int qo = l - (int)bq * 59;
            const float4 x = *(const float4*)(best    + ((size_t)l << 2));
            const float4 g = *(const float4*)(best_gt + ((size_t)l << 2));
            const float* xp = (const float*)&x;
            const float* gp = (const float*)&g;
            const int p2 = qo << 1;
            #pragma unroll
            for (int jj = 0; jj < 4; ++jj) {
                const int p = p2 + (jj >> 1);
                const bool marked = (p == 0) | (p == 29) | (p == 88) | (p == 117);
                const float wgt = w_best + (marked ? w_bland : 0.0f);
                const float d = xp[jj] - gp[jj];
                acc += wgt * d * d;
            }
        }
    }

    // wave (64-lane) shuffle reduction
    #pragma unroll
    for (int o = 32; o > 0; o >>= 1) acc += __shfl_down(acc, o, 64);

    __shared__ float wsum[4];
    const int wave = t >> 6;
    if ((t & 63) == 0) wsum[wave] = acc;
    __syncthreads();
    if (t == 0) partials[blk] = wsum[0] + wsum[1] + wsum[2] + wsum[3];
}

__global__ __launch_bounds__(256) void cq_reduce(
    const float* __restrict__ partials, float* __restrict__ out)
{
    const int t = threadIdx.x;
    float acc = 0.0f;
    for (int i = t; i < TOTAL_BLOCKS; i += 256) acc += partials[i];
    #pragma unroll
    for (int o = 32; o > 0; o >>= 1) acc += __shfl_down(acc, o, 64);
    __shared__ float wsum[4];
    if ((t & 63) == 0) wsum[t >> 6] = acc;
    __syncthreads();
    if (t == 0) out[0] = wsum[0] + wsum[1] + wsum[2] + wsum[3];
}

extern "C" void kernel_launch(void* const* d_in, const int* in_sizes, int n_in,
                              void* d_out, int out_size, void* d_ws, size_t ws_size,
                              hipStream_t stream) {
    const float* zs      = (const float*)d_in[0];
    const float* rzs     = (const float*)d_in[1];
    const float* pts     = (const float*)d_in[2];
    const float* pts_gt  = (const float*)d_in[3];
    const float* qy      = (const float*)d_in[4];
    // d_in[5] = logits: unused by the reference
    const float* best    = (const float*)d_in[6];
    const float* best_gt = (const float*)d_in[7];
    const int*   mapping = (const int*)d_in[8];
    const int*   vd      = (const int*)d_in[9];
    float* out      = (float*)d_out;
    float* partials = (float*)d_ws;   // TOTAL_BLOCKS floats — fully overwritten each call

    cq_main<<<TOTAL_BLOCKS, 256, 0, stream>>>(zs, rzs, pts, pts_gt, qy,
                                              best, best_gt, mapping, vd, partials);
    cq_reduce<<<1, 256, 0, stream>>>(partials, out);
}

// Round 6
// 177.795 us; speedup vs baseline: 1.0770x; 1.0770x over previous
//
#include <hip/hip_runtime.h>
#include <math.h>

// Problem constants (B,S,D,P,C,V) = (64,128,2048,118,2,512)
#define NB 64
#define NS 128
#define ND 2048
#define NP 118
#define NC 2
#define NV 512

// Block partitioning (uniform control flow per block) — R2 structure:
constexpr int RECON_BLOCKS = 2048;  // 4 rows (4*2048 floats) per block
constexpr int KLD_BLOCKS   = 512;   // 2048 vec4 per block
constexpr int PTS_BLOCKS   = 512;   // 16 rows (16*59=944 vec4) per block
constexpr int BEST_BLOCKS  = 16;    // 236 vec4 per block
constexpr int TOTAL_BLOCKS = RECON_BLOCKS + KLD_BLOCKS + PTS_BLOCKS + BEST_BLOCKS; // 3088

// Native vector type so __builtin_nontemporal_load lowers to global_load_dwordx4 nt
typedef float f4v __attribute__((ext_vector_type(4)));

__device__ __forceinline__ f4v ntload(const float* p) {
    return __builtin_nontemporal_load((const f4v*)p);
}

__global__ __launch_bounds__(256) void cq_main(
    const float* __restrict__ zs, const float* __restrict__ rzs,
    const float* __restrict__ pts, const float* __restrict__ pts_gt,
    const float* __restrict__ qy,
    const float* __restrict__ best, const float* __restrict__ best_gt,
    const int* __restrict__ mapping, const int* __restrict__ vd,
    float* __restrict__ partials)
{
    const float w_recon = 1.0f / 16777216.0f;          // GAMMA / (B*S*D)
    const float w_kld   = 0.1f / 8192.0f;              // BETA / (B*S)
    const float w_disk  = 1.0f / 1933312.0f;           // 1 / (B*S*P*C)
    const float w_land  = 10.0f / 65536.0f;            // ALPHA / (B*S*4*C)
    const float w_best  = 1.0f / 15104.0f;             // 1 / (B*P*C)
    const float w_bland = 10.0f / 512.0f;              // ALPHA / (B*4*C)

    const int t   = threadIdx.x;
    const int blk = blockIdx.x;
    float acc = 0.0f;

    __shared__ int mrow[16];   // pts region only

    if (blk < RECON_BLOCKS) {
        // ---- recon: mse(rzs[b, m[b,s], :], zs[b, s, :]) — 4 rows per block
        const int r0 = blk << 2;            // 4-row group never crosses batch
        const int b  = r0 >> 7;
        const int m0 = mapping[r0];
        const int m1 = mapping[r0 + 1];
        const int m2 = mapping[r0 + 2];
        const int m3 = mapping[r0 + 3];
        const float* zb = zs  + ((size_t)r0 << 11);    // 2048 floats per row
        const float* rz = rzs + ((size_t)b << 18);     // b * 128 * 2048
        const size_t rb0 = (size_t)m0 << 11, rb1 = (size_t)m1 << 11;
        const size_t rb2 = (size_t)m2 << 11, rb3 = (size_t)m3 << 11;
        const int e = t << 2;                          // element offset 0..1023*? (t*4)

        f4v z[8], r[8];
        #pragma unroll
        for (int k = 0; k < 8; ++k) z[k] = ntload(zb + ((size_t)k << 10) + e);
        r[0] = ntload(rz + rb0 + e);        r[1] = ntload(rz + rb0 + 1024 + e);
        r[2] = ntload(rz + rb1 + e);        r[3] = ntload(rz + rb1 + 1024 + e);
        r[4] = ntload(rz + rb2 + e);        r[5] = ntload(rz + rb2 + 1024 + e);
        r[6] = ntload(rz + rb3 + e);        r[7] = ntload(rz + rb3 + 1024 + e);

        float s = 0.0f;
        #pragma unroll
        for (int k = 0; k < 8; ++k) {
            f4v d = r[k] - z[k];
            s += d.x*d.x + d.y*d.y + d.z*d.z + d.w*d.w;
        }
        acc = w_recon * s;
    } else if (blk < RECON_BLOCKS + KLD_BLOCKS) {
        // ---- kld vs uniform: 2048 vec4 per block, 8 per thread
        const int rb = blk - RECON_BLOCKS;
        const float log_g = -__logf((float)vd[0]);     // log(1/V), scalar
        const float* qp = qy + ((size_t)rb << 13) + (t << 2);
        f4v q[8];
        #pragma unroll
        for (int k = 0; k < 8; ++k) q[k] = ntload(qp + (k << 10));
        float s = 0.0f;
        #pragma unroll
        for (int k = 0; k < 8; ++k) {
            s += q[k].x * (__logf(q[k].x + 1e-20f) - log_g)
               + q[k].y * (__logf(q[k].y + 1e-20f) - log_g)
               + q[k].z * (__logf(q[k].z + 1e-20f) - log_g)
               + q[k].w * (__logf(q[k].w + 1e-20f) - log_g);
        }
        acc = w_kld * s;
    } else if (blk < RECON_BLOCKS + KLD_BLOCKS + PTS_BLOCKS) {
        // ---- pts: disk + ALPHA*landmark over gathered rows; 16 rows per block
        const int rb = blk - (RECON_BLOCKS + KLD_BLOCKS);
        if (t < 16) mrow[t] = mapping[(rb << 4) + t];
        __syncthreads();
        const int bs_base = rb << 4;
        f4v x[4], g[4];
        int pbase[4];
        #pragma unroll
        for (int j = 0; j < 4; ++j) {
            const int w = t + j * 256;
            const unsigned rl = (unsigned)w / 59u;     // row_local
            const int qo = w - (int)rl * 59;
            const bool valid = (w < 944);
            const int rl_c = valid ? (int)rl : 0;
            const int bs = bs_base + rl_c;
            const int b  = bs >> 7;
            const int m  = mrow[rl_c];
            const size_t xi = (size_t)((b << 7) + m) * 236 + (qo << 2);
            const size_t gi = (size_t)(rb * 944 + w) << 2;
            pbase[j] = valid ? (qo << 1) : -100;
            x[j] = valid ? ntload(pts    + xi) : (f4v)(0.0f);
            g[j] = valid ? ntload(pts_gt + gi) : (f4v)(0.0f);
        }
        #pragma unroll
        for (int j = 0; j < 4; ++j) {
            #pragma unroll
            for (int jj = 0; jj < 4; ++jj) {
                const int p = pbase[j] + (jj >> 1);
                const bool marked = (p == 0) | (p == 29) | (p == 88) | (p == 117);
                const float wgt = w_disk + (marked ? w_land : 0.0f);
                const float d = x[j][jj] - g[j][jj];
                acc += wgt * d * d;
            }
        }
    } else {
        // ---- best: full mse + ALPHA*landmark, 236 vec4 per block
        const int db = blk - (RECON_BLOCKS + KLD_BLOCKS + PTS_BLOCKS);
        if (t < 236) {
            const int l = db * 236 + t;                // global vec4 index
            const unsigned bq = (unsigned)l / 59u;
            const int qo = l - (int)bq * 59;
            const f4v x = ntload(best    + ((size_t)l << 2));
            const f4v g = ntload(best_gt + ((size_t)l << 2));
            const int p2 = qo << 1;
            #pragma unroll
            for (int jj = 0; jj < 4; ++jj) {
                const int p = p2 + (jj >> 1);
                const bool marked = (p == 0) | (p == 29) | (p == 88) | (p == 117);
                const float wgt = w_best + (marked ? w_bland : 0.0f);
                const float d = x[jj] - g[jj];
                acc += wgt * d * d;
            }
        }
    }

    // wave (64-lane) shuffle reduction
    #pragma unroll
    for (int o = 32; o > 0; o >>= 1) acc += __shfl_down(acc, o, 64);

    __shared__ float wsum[4];
    if ((t & 63) == 0) wsum[t >> 6] = acc;
    __syncthreads();
    if (t == 0) partials[blk] = wsum[0] + wsum[1] + wsum[2] + wsum[3];
}

__global__ __launch_bounds__(256) void cq_reduce(
    const float* __restrict__ partials, float* __restrict__ out)
{
    const int t = threadIdx.x;
    float acc = 0.0f;
    for (int i = t; i < TOTAL_BLOCKS; i += 256) acc += partials[i];
    #pragma unroll
    for (int o = 32; o > 0; o >>= 1) acc += __shfl_down(acc, o, 64);
    __shared__ float wsum[4];
    if ((t & 63) == 0) wsum[t >> 6] = acc;
    __syncthreads();
    if (t == 0) out[0] = wsum[0] + wsum[1] + wsum[2] + wsum[3];
}

extern "C" void kernel_launch(void* const* d_in, const int* in_sizes, int n_in,
                              void* d_out, int out_size, void* d_ws, size_t ws_size,
                              hipStream_t stream) {
    const float* zs      = (const float*)d_in[0];
    const float* rzs     = (const float*)d_in[1];
    const float* pts     = (const float*)d_in[2];
    const float* pts_gt  = (const float*)d_in[3];
    const float* qy      = (const float*)d_in[4];
    // d_in[5] = logits: unused by the reference
    const float* best    = (const float*)d_in[6];
    const float* best_gt = (const float*)d_in[7];
    const int*   mapping = (const int*)d_in[8];
    const int*   vd      = (const int*)d_in[9];
    float* out      = (float*)d_out;
    float* partials = (float*)d_ws;   // TOTAL_BLOCKS floats — fully overwritten each call

    cq_main<<<TOTAL_BLOCKS, 256, 0, stream>>>(zs, rzs, pts, pts_gt, qy,
                                              best, best_gt, mapping, vd, partials);
    cq_reduce<<<1, 256, 0, stream>>>(partials, out);
}